// Round 8
// baseline (174.632 us; speedup 1.0000x reference)
//
#include <hip/hip_runtime.h>
#include <hip/hip_bf16.h>

typedef short short8 __attribute__((ext_vector_type(8)));
typedef short short4_t __attribute__((ext_vector_type(4)));
typedef float floatx4 __attribute__((ext_vector_type(4)));

#define DEVI __device__ __forceinline__

// Dims: B=4, T=4096, D=256, E=12 (4x k5, 4x k9, 4x k17), 16384 tokens.
// fp32 in/out; MFMA operands bf16.
//
// R8: wave-staggered producer/consumer. R2/R3/R6/R7 proved the allocator
//   pins arch-VGPR at <=128 for this shape (spills any larger live set), and
//   R5 proved conv-from-LDS is free. So: get conv(VALU) || gemm(MFMA)
//   overlap from WAVE scheduling, not per-thread fusion:
//     waves 0-3: produce(c+1) -> gemm(c);  waves 4-7: gemm(c) -> produce(c+1)
//   One barrier per region. Each SIMD hosts one conv-phase + one gemm-phase
//   wave at any time -> VALU and matrix pipes run concurrently; cf/B load
//   latency hidden by the partner wave. All phases live-set <=~110 VGPR:
//   conv window from LDS (xs resident), B inline distance-1, cf loaded
//   inside the phase branch. LDS 118KB dynamic (1 blk/CU as before).
//
// ws: projWT bf16 [12][256f][256d] @ 0         (1,572,864)
//     outWT  bf16 [256f][256k]     @ 1,572,864 (131,072)
//     projbT bf16 [256n][32k]      @ 1,703,936 (16,384)  (k>=12 zero)
//     rWT    bf16 [16e][256d]      @ 1,720,320 (8,192)   (e>=12 zero)

DEVI float bf2f(__hip_bfloat16 v) { return __bfloat162float(v); }
DEVI __hip_bfloat16 f2bf(float v) { return __float2bfloat16(v); }
DEVI unsigned short bfbits(float v) { __hip_bfloat16 b = f2bf(v); return *(unsigned short*)&b; }

// ---------------------------------------------------------------- prep ----
// 209 blocks: 0..191 projW 64x64 transpose tiles, 192..207 outW, 208 misc.
__global__ __launch_bounds__(256) void prep_kernel(
    const float* __restrict__ rW,      // [256][12]
    const float* __restrict__ projW,   // [12][256d][256f]
    const float* __restrict__ outW,    // [256k][256f]
    const float* __restrict__ projb,   // [12][256]
    __hip_bfloat16* __restrict__ projWT,
    __hip_bfloat16* __restrict__ outWT,
    __hip_bfloat16* __restrict__ projbT,
    __hip_bfloat16* __restrict__ rWT)
{
    __shared__ __align__(16) __hip_bfloat16 Tt[64 * 72];
    const int bid = blockIdx.x;
    const int tid = threadIdx.x;

    if (bid == 208) {
#pragma unroll
        for (int k = 0; k < 32; k++)
            projbT[tid * 32 + k] = (k < 12) ? f2bf(projb[k * 256 + tid]) : f2bf(0.f);
#pragma unroll
        for (int e = 0; e < 16; e++)
            rWT[e * 256 + tid] = (e < 12) ? f2bf(rW[tid * 12 + e]) : f2bf(0.f);
        return;
    }
    const float* src;
    __hip_bfloat16* dst;
    if (bid < 192) {
        int e = bid >> 4, ti = (bid & 15) >> 2, tj = bid & 3;
        src = projW + (e << 16) + (ti * 64) * 256 + tj * 64;
        dst = projWT + (e << 16) + (tj * 64) * 256 + ti * 64;
    } else {
        int b3 = bid - 192, ti = b3 >> 2, tj = b3 & 3;
        src = outW + (ti * 64) * 256 + tj * 64;
        dst = outWT + (tj * 64) * 256 + ti * 64;
    }
#pragma unroll
    for (int i = 0; i < 4; i++) {
        int r = i * 16 + (tid >> 4);
        int c4 = (tid & 15) * 4;
        float4 f = *(const float4*)(src + r * 256 + c4);
        Tt[(c4 + 0) * 72 + r] = f2bf(f.x);
        Tt[(c4 + 1) * 72 + r] = f2bf(f.y);
        Tt[(c4 + 2) * 72 + r] = f2bf(f.z);
        Tt[(c4 + 3) * 72 + r] = f2bf(f.w);
    }
    __syncthreads();
#pragma unroll
    for (int i = 0; i < 2; i++) {
        int c = i * 32 + (tid >> 3);
        int r8 = (tid & 7) * 8;
        *(short8*)(dst + c * 256 + r8) = *(const short8*)(Tt + c * 72 + r8);
    }
}

// --------------------------------------------------------------- fused ----
// Dynamic LDS map (118,016 B, 1 block/CU):
//   xs    bf16 [80][264] @ 0        (42,240)  x tile (resident all chunks)
//   bufA  bf16 [64][264] @ 42,240   (33,792)
//   bufB  bf16 [64][264] @ 76,032   (33,792)
//   wts_s f32  [12][64]  @ 109,824  ( 3,072)
//   psum  f32  [64][9]   @ 112,896  ( 2,304)
//   psq   f32  [64][9]   @ 115,200  ( 2,304)
//   muA   f32  [64]      @ 117,504  rsA f32 [64] @ 117,760
constexpr int SMEM_BYTES = 118016;

// conv from LDS window (shift register), 16 t-rows x 2 packed ch per thread.
template<int K>
DEVI void conv_lds2(const float2 (&cf)[17], const unsigned* __restrict__ xsu,
                    int tloc, int du, const float4 (&wt4)[4],
                    unsigned* __restrict__ dp)
{
    unsigned w[16];
#pragma unroll
    for (int i = 0; i < K - 1; i++)
        w[i] = xsu[(16 + tloc - (K - 1) + i) * 132 + du];
#pragma unroll
    for (int t = 0; t < 16; t++) {
        unsigned nv = xsu[(16 + tloc + t) * 132 + du];
        float y0 = cf[K - 1].x * __uint_as_float(nv << 16);
        float y1 = cf[K - 1].y * __uint_as_float(nv & 0xffff0000u);
#pragma unroll
        for (int i = 0; i < K - 1; i++) {
            y0 = fmaf(cf[i].x, __uint_as_float(w[i] << 16), y0);
            y1 = fmaf(cf[i].y, __uint_as_float(w[i] & 0xffff0000u), y1);
        }
        float wt = wt4[t >> 2][t & 3];
        unsigned pv = ((unsigned)bfbits(y1 * wt) << 16) | (unsigned)bfbits(y0 * wt);
        dp[t * 132] = pv;
#pragma unroll
        for (int i = 0; i + 1 < K - 1; i++) w[i] = w[i + 1];
        if (K > 1) w[K - 2] = nv;
    }
}

// GEMM, inline B with distance-1 prefetch: M=64 (4 mf) x N=32 (2 nt) x K=NKS*32.
template<int NKS>
DEVI void gemm_inl(const __hip_bfloat16* __restrict__ A, int astride,
                   const __hip_bfloat16* __restrict__ Bg, int bstride,
                   floatx4 (&acc)[4][2], int l16, int quad, int nsl)
{
    const __hip_bfloat16* ap = A + l16 * astride + quad * 8;
    const __hip_bfloat16* bp = Bg + (nsl + l16) * bstride + quad * 8;
    short8 a[4], b[2];
#pragma unroll
    for (int mf = 0; mf < 4; mf++) a[mf] = *(const short8*)(ap + mf * 16 * astride);
#pragma unroll
    for (int nt = 0; nt < 2; nt++) b[nt] = *(const short8*)(bp + nt * 16 * bstride);
#pragma unroll
    for (int ks = 0; ks < NKS; ks++) {
        short8 na[4], nb[2];
        if (ks < NKS - 1) {
#pragma unroll
            for (int mf = 0; mf < 4; mf++)
                na[mf] = *(const short8*)(ap + mf * 16 * astride + (ks + 1) * 32);
#pragma unroll
            for (int nt = 0; nt < 2; nt++)
                nb[nt] = *(const short8*)(bp + nt * 16 * bstride + (ks + 1) * 32);
        }
#pragma unroll
        for (int nt = 0; nt < 2; nt++)
#pragma unroll
            for (int mf = 0; mf < 4; mf++)
                acc[mf][nt] = __builtin_amdgcn_mfma_f32_16x16x32_bf16(
                    a[mf], b[nt], acc[mf][nt], 0, 0, 0);
        if (ks < NKS - 1) {
#pragma unroll
            for (int mf = 0; mf < 4; mf++) a[mf] = na[mf];
#pragma unroll
            for (int nt = 0; nt < 2; nt++) b[nt] = nb[nt];
        }
    }
}

__global__ __launch_bounds__(512, 1) void fused_kernel(
    const float* __restrict__ x,
    const float* __restrict__ ck5, const float* __restrict__ ck9,
    const float* __restrict__ ck17,
    const float* __restrict__ rb,      // [12]
    const float* __restrict__ gmm, const float* __restrict__ bta,
    const float* __restrict__ outb,
    const __hip_bfloat16* __restrict__ projWT,
    const __hip_bfloat16* __restrict__ outWT,
    const __hip_bfloat16* __restrict__ projbT,
    const __hip_bfloat16* __restrict__ rWT,
    float* __restrict__ out)
{
    extern __shared__ char smem[];
    __hip_bfloat16* xs   = (__hip_bfloat16*)smem;             // [80][264]
    __hip_bfloat16* bufA = (__hip_bfloat16*)(smem + 42240);   // [64][264]
    __hip_bfloat16* bufB = (__hip_bfloat16*)(smem + 76032);   // [64][264]
    float* wts_s = (float*)(smem + 109824);                   // [12][64]
    float* psum  = (float*)(smem + 112896);                   // [64][9]
    float* psq   = (float*)(smem + 115200);                   // [64][9]
    float* muA   = (float*)(smem + 117504);
    float* rsA   = (float*)(smem + 117760);
    const unsigned* xsu = (const unsigned*)xs;

    const int tid  = threadIdx.x;
    const int wave = tid >> 6;                 // 0..7
    const int lane = tid & 63;
    const int quad = lane >> 4;
    const int l16  = lane & 15;
    const int nsl  = wave * 32;                // 32-wide f-slice per wave
    const bool gemmFirst = (wave >= 4);        // SIMD i hosts waves i and i+4
    const int m0   = blockIdx.x * 64;
    const int bb   = m0 >> 12;
    const int t0   = m0 & 4095;

    // ---- stage x tile rows t0-16..t0+63, fp32 -> bf16 ----
    {
        const float* xb = x + (size_t)bb * 4096 * 256;
        for (int idx = tid; idx < 80 * 64; idx += 512) {
            int row = idx >> 6, c4 = (idx & 63) << 2;
            int gt = t0 - 16 + row;
            short4_t v = {0, 0, 0, 0};
            if (gt >= 0) {
                float4 f = *(const float4*)(xb + (size_t)gt * 256 + c4);
                v[0] = (short)bfbits(f.x); v[1] = (short)bfbits(f.y);
                v[2] = (short)bfbits(f.z); v[3] = (short)bfbits(f.w);
            }
            *(short4_t*)(xs + row * 264 + c4) = v;
        }
    }
    __syncthreads();

    // ---- router (waves 0..3): MFMA logits + shuffle softmax -> wts_s[12][64]
    if (wave < 4) {
        floatx4 ra = {0.f, 0.f, 0.f, 0.f};
        const __hip_bfloat16* ap = xs + (16 + wave * 16 + l16) * 264 + quad * 8;
        const __hip_bfloat16* bp = rWT + l16 * 256 + quad * 8;
#pragma unroll
        for (int kk = 0; kk < 256; kk += 32)
            ra = __builtin_amdgcn_mfma_f32_16x16x32_bf16(
                *(const short8*)(ap + kk), *(const short8*)(bp + kk), ra, 0, 0, 0);
        float rbv = (l16 < 12) ? rb[l16] : 0.f;
#pragma unroll
        for (int r = 0; r < 4; r++) {
            float v = (l16 < 12) ? (ra[r] + rbv) : -1e30f;
            float mx = v;
            mx = fmaxf(mx, __shfl_xor(mx, 1));
            mx = fmaxf(mx, __shfl_xor(mx, 2));
            mx = fmaxf(mx, __shfl_xor(mx, 4));
            mx = fmaxf(mx, __shfl_xor(mx, 8));
            float ex = (l16 < 12) ? __expf(v - mx) : 0.f;
            float sm = ex;
            sm += __shfl_xor(sm, 1);
            sm += __shfl_xor(sm, 2);
            sm += __shfl_xor(sm, 4);
            sm += __shfl_xor(sm, 8);
            if (l16 < 12) wts_s[l16 * 64 + (wave * 16 + quad * 4 + r)] = ex / sm;
        }
    }
    __syncthreads();                           // wts_s ready; xs resident

    const int d0   = 2 * (tid & 127);          // 0..254 (2 packed channels)
    const int du   = d0 >> 1;                  // uint index in a row
    const int tloc = (tid >> 7) * 16;          // 0/16/32/48

    // ---- helpers -------------------------------------------------------
    auto loadCoef = [&](float2 (&cf)[17], int e) {
        if (e < 4) {
            const float* cw = ck5 + e * 5 * 256;
#pragma unroll
            for (int j = 0; j < 17; j++)
                cf[j] = (j < 5) ? *(const float2*)(cw + j * 256 + d0) : make_float2(0.f, 0.f);
        } else if (e < 8) {
            const float* cw = ck9 + (e - 4) * 9 * 256;
#pragma unroll
            for (int j = 0; j < 17; j++)
                cf[j] = (j < 9) ? *(const float2*)(cw + j * 256 + d0) : make_float2(0.f, 0.f);
        } else {
            const float* cw = ck17 + (e - 8) * 17 * 256;
#pragma unroll
            for (int j = 0; j < 17; j++)
                cf[j] = *(const float2*)(cw + j * 256 + d0);
        }
    };
    auto produce = [&](int e, __hip_bfloat16* dst) {   // conv expert e -> dst
        float2 cf[17];
        loadCoef(cf, e);
        float4 wt4[4];
#pragma unroll
        for (int g = 0; g < 4; g++)
            wt4[g] = *(const float4*)(wts_s + e * 64 + tloc + 4 * g);
        unsigned* dp = (unsigned*)dst + tloc * 132 + du;
        if (e < 4)      conv_lds2<5>(cf, xsu, tloc, du, wt4, dp);
        else if (e < 8) conv_lds2<9>(cf, xsu, tloc, du, wt4, dp);
        else            conv_lds2<17>(cf, xsu, tloc, du, wt4, dp);
    };
    auto produceBias = [&](__hip_bfloat16* dst) {
        int t = tid >> 3, k4 = (tid & 7) * 4;
        short4_t v;
#pragma unroll
        for (int j = 0; j < 4; j++) {
            int k = k4 + j;
            v[j] = (k < 12) ? (short)bfbits(wts_s[k * 64 + t]) : (short)0;
        }
        *(short4_t*)(dst + t * 264 + k4) = v;
    };

    floatx4 acc[4][2];
#pragma unroll
    for (int i = 0; i < 4; i++)
#pragma unroll
        for (int j = 0; j < 2; j++) acc[i][j] = {0.f, 0.f, 0.f, 0.f};

    __hip_bfloat16* bufC = bufA;               // chunk being gemm'd
    __hip_bfloat16* bufN = bufB;               // chunk being produced

    // prologue: produce expert 0 (all waves)
    produce(0, bufC);
    __syncthreads();

    // Regions r=0..10: gemm expert r from bufC + produce expert r+1 -> bufN.
    // Staggered order: waves 0-3 conv->gemm, waves 4-7 gemm->conv.
#pragma unroll 1
    for (int r = 0; r < 11; r++) {
        const __hip_bfloat16* Bg = projWT + ((size_t)r << 16);
        if (gemmFirst) {
            gemm_inl<8>(bufC, 264, Bg, 256, acc, l16, quad, nsl);
            produce(r + 1, bufN);
        } else {
            produce(r + 1, bufN);
            gemm_inl<8>(bufC, 264, Bg, 256, acc, l16, quad, nsl);
        }
        { __hip_bfloat16* t_ = bufC; bufC = bufN; bufN = t_; }
        __syncthreads();
    }
    // Region 11: gemm expert 11 + produce bias chunk
    {
        const __hip_bfloat16* Bg = projWT + ((size_t)11 << 16);
        if (gemmFirst) {
            gemm_inl<8>(bufC, 264, Bg, 256, acc, l16, quad, nsl);
            produceBias(bufN);
        } else {
            produceBias(bufN);
            gemm_inl<8>(bufC, 264, Bg, 256, acc, l16, quad, nsl);
        }
        { __hip_bfloat16* t_ = bufC; bufC = bufN; bufN = t_; }
        __syncthreads();
    }
    // bias chunk: A = router wts [64][32] in bufC, B = projbT
    gemm_inl<1>(bufC, 264, projbT, 32, acc, l16, quad, nsl);

    // ---- LN stats from accumulators (exact fp32) ----
    {
        float s[16], s2[16];
#pragma unroll
        for (int mf = 0; mf < 4; mf++)
#pragma unroll
            for (int r = 0; r < 4; r++) {
                int i = mf * 4 + r;
                float v = 0.f, q = 0.f;
#pragma unroll
                for (int nt = 0; nt < 2; nt++) {
                    float a = acc[mf][nt][r];
                    v += a; q += a * a;
                }
                s[i] = v; s2[i] = q;
            }
#pragma unroll
        for (int m = 1; m <= 8; m <<= 1)
#pragma unroll
            for (int i = 0; i < 16; i++) {
                s[i]  += __shfl_xor(s[i], m);
                s2[i] += __shfl_xor(s2[i], m);
            }
#pragma unroll
        for (int i = 0; i < 16; i++)
            if (l16 == i) {
                int row = (i >> 2) * 16 + quad * 4 + (i & 3);
                psum[row * 9 + wave] = s[i];
                psq[row * 9 + wave]  = s2[i];
            }
    }
    __syncthreads();
    if (tid < 64) {
        float ss = 0.f, qq = 0.f;
#pragma unroll
        for (int p = 0; p < 8; p++) { ss += psum[tid * 9 + p]; qq += psq[tid * 9 + p]; }
        float mu = ss * 0.00390625f;
        float var = fmaxf(qq * 0.00390625f - mu * mu, 0.f);
        muA[tid] = mu;
        rsA[tid] = rsqrtf(var + 1e-5f);
    }
    __syncthreads();

    // ---- normalize acc -> normed bf16 [64][264] (bufN: free buffer) ----
    __hip_bfloat16* normed = bufN;
#pragma unroll
    for (int nt = 0; nt < 2; nt++) {
        int col = nsl + nt * 16 + l16;
        float g = gmm[col], bt = bta[col];
#pragma unroll
        for (int mf = 0; mf < 4; mf++)
#pragma unroll
            for (int r = 0; r < 4; r++) {
                int row = mf * 16 + quad * 4 + r;
                normed[row * 264 + col] =
                    f2bf((acc[mf][nt][r] - muA[row]) * rsA[row] * g + bt);
            }
    }
    __syncthreads();

    // ---- out = normed @ out_W + out_b (inline B) ----
    floatx4 acc2[4][2];
#pragma unroll
    for (int i = 0; i < 4; i++)
#pragma unroll
        for (int j = 0; j < 2; j++) acc2[i][j] = {0.f, 0.f, 0.f, 0.f};
    gemm_inl<8>(normed, 264, outWT, 256, acc2, l16, quad, nsl);

    float* op = out + (size_t)m0 * 256;
#pragma unroll
    for (int nt = 0; nt < 2; nt++) {
        int col = nsl + nt * 16 + l16;
        float ob = outb[col];
#pragma unroll
        for (int mf = 0; mf < 4; mf++)
#pragma unroll
            for (int r = 0; r < 4; r++) {
                int row = mf * 16 + quad * 4 + r;
                op[row * 256 + col] = acc2[mf][nt][r] + ob;
            }
    }
}

// -------------------------------------------------------------- launch ----
extern "C" void kernel_launch(void* const* d_in, const int* in_sizes, int n_in,
                              void* d_out, int out_size, void* d_ws, size_t ws_size,
                              hipStream_t stream)
{
    (void)in_sizes; (void)n_in; (void)out_size; (void)ws_size;
    const float* x     = (const float*)d_in[0];
    const float* ck5   = (const float*)d_in[1];
    const float* ck9   = (const float*)d_in[2];
    const float* ck17  = (const float*)d_in[3];
    const float* projW = (const float*)d_in[4];
    const float* projb = (const float*)d_in[5];
    const float* rW    = (const float*)d_in[6];
    const float* rb    = (const float*)d_in[7];
    const float* outW  = (const float*)d_in[8];
    const float* outb  = (const float*)d_in[9];
    const float* gmm   = (const float*)d_in[10];
    const float* bta   = (const float*)d_in[11];

    __hip_bfloat16* projWT = (__hip_bfloat16*)d_ws;
    __hip_bfloat16* outWT  = (__hip_bfloat16*)((char*)d_ws + 1572864);
    __hip_bfloat16* projbT = (__hip_bfloat16*)((char*)d_ws + 1703936);
    __hip_bfloat16* rWT    = (__hip_bfloat16*)((char*)d_ws + 1720320);

    static bool attr_set = false;
    if (!attr_set) {
        hipFuncSetAttribute((const void*)fused_kernel,
                            hipFuncAttributeMaxDynamicSharedMemorySize, SMEM_BYTES);
        attr_set = true;
    }

    prep_kernel<<<dim3(209), dim3(256), 0, stream>>>(
        rW, projW, outW, projb, projWT, outWT, projbT, rWT);
    fused_kernel<<<dim3(256), dim3(512), SMEM_BYTES, stream>>>(
        x, ck5, ck9, ck17, rb, gmm, bta, outb,
        projWT, outWT, projbT, rWT, (float*)d_out);
}